// Round 14
// baseline (133.775 us; speedup 1.0000x reference)
//
#include <hip/hip_runtime.h>
#include <hip/hip_bf16.h>
#include <math.h>

typedef __attribute__((ext_vector_type(4))) float floatx4;
typedef __attribute__((ext_vector_type(8))) __bf16 bf16x8;

#define B_ROWS 4096
#define D_DIM  1024
#define C_CUR  1000
#define P_PREV 2000
#define C_PAD  1024
#define P_PAD  2048
#define N_TOT  (C_PAD + P_PAD)   // 3072

// NOTE: __builtin_amdgcn_global_load_lds is BANNED this session: 4/4 container
// deaths (R4-R6, R8) vs clean runs without.
// Barrier without vmcnt drain (prefetch loads stay in flight).
#define LDS_BARRIER() asm volatile("s_waitcnt lgkmcnt(0)\n\ts_barrier" ::: "memory")

__device__ __forceinline__ float wave_sum(float v) {
#pragma unroll
  for (int o = 32; o > 0; o >>= 1) v += __shfl_xor(v, o, 64);
  return v;
}
__device__ __forceinline__ float wave_max(float v) {
#pragma unroll
  for (int o = 32; o > 0; o >>= 1) v = fmaxf(v, __shfl_xor(v, o, 64));
  return v;
}

// float -> OCP e4m3fn, RNE, manual (values here are |x| <= 1, no NaN/inf).
__device__ __forceinline__ unsigned char f32_to_e4m3(float x) {
  unsigned u = __float_as_uint(x);
  unsigned s = (u >> 24) & 0x80u;
  float a = fabsf(x);
  if (a < 0.015625f) {                    // subnormal: step 2^-9
    int q = (int)rintf(a * 512.0f);       // 0..8; 8 rolls into exp=1,m=0 (2^-6)
    return (unsigned char)(s | (unsigned)q);
  }
  unsigned au = u & 0x7fffffffu;
  unsigned r = au + 0x0007ffffu + ((au >> 20) & 1u);  // RNE at bit 20
  int e = (int)(r >> 23) - 127;
  unsigned m = (r >> 20) & 7u;
  return (unsigned char)(s | ((unsigned)(e + 7) << 3) | m);
}

// ---------------------------------------------------------------------------
// Fused L2-normalize -> fp8 e4m3. One WAVE per row; lane owns 16 contiguous
// elements. Pad rows zero-filled.
// ---------------------------------------------------------------------------
__global__ __launch_bounds__(256) void norm_all_kernel(
    const float* __restrict__ features, const float* __restrict__ cur_proto,
    const float* __restrict__ prev_proto, unsigned char* __restrict__ fn,
    unsigned char* __restrict__ proto) {
  const int wv = threadIdx.x >> 6, lane = threadIdx.x & 63;
  const int r = blockIdx.x * 4 + wv;
  const float* src;
  unsigned char* dst;
  bool valid;
  if (r < B_ROWS) {
    src = features + (size_t)r * D_DIM;
    dst = fn + (size_t)r * D_DIM;
    valid = true;
  } else if (r < B_ROWS + C_PAD) {
    const int rr = r - B_ROWS;
    src = cur_proto + (size_t)rr * D_DIM;
    dst = proto + (size_t)rr * D_DIM;
    valid = rr < C_CUR;
  } else {
    const int rr = r - B_ROWS - C_PAD;
    src = prev_proto + (size_t)rr * D_DIM;
    dst = proto + (size_t)(C_PAD + rr) * D_DIM;
    valid = rr < P_PREV;
  }
  if (!valid) {
    uint4 z = {0, 0, 0, 0};
    *(uint4*)(dst + lane * 16) = z;
    return;
  }
  float4 v[4];
  float ss = 0.f;
#pragma unroll
  for (int k = 0; k < 4; ++k) {
    v[k] = *(const float4*)(src + lane * 16 + k * 4);
    ss += v[k].x * v[k].x + v[k].y * v[k].y + v[k].z * v[k].z + v[k].w * v[k].w;
  }
  ss = wave_sum(ss);
  const float inv = 1.0f / fmaxf(sqrtf(ss), 1e-12f);
  union { unsigned char b[16]; uint4 q; } o;
#pragma unroll
  for (int k = 0; k < 4; ++k) {
    o.b[k * 4 + 0] = f32_to_e4m3(v[k].x * inv);
    o.b[k * 4 + 1] = f32_to_e4m3(v[k].y * inv);
    o.b[k * 4 + 2] = f32_to_e4m3(v[k].z * inv);
    o.b[k * 4 + 3] = f32_to_e4m3(v[k].w * inv);
  }
  *(uint4*)(dst + lane * 16) = o.q;
}

// ---------------------------------------------------------------------------
// GEMM fp8: C = A*B^T, fp8 e4m3 in, bf16 out, fp32 accum.
// 128(M) x 64(N) tile, BK=32B -> grid 48x32 = 1536 blocks = 6/CU = 24
// waves/CU (75% occupancy ceiling vs 37.5% at 128x128 -- R3 counters showed
// Occupancy 24%, everything idle: latency-bound for lack of waves).
// 4 waves in 2x2; wave tile 64x32 = 4x2 frags of 16x16x32 fp8 (acc 32 VGPR).
// LDS stride 48B; dbuf + 1-deep register prefetch + lgkm-only s_barrier.
// C/D map (m89/m91): row=(lane>>4)*4+reg, col=lane&15.
// ---------------------------------------------------------------------------
#define TMM   128                // M tile
#define TNN   64                 // N tile
#define BK    32
#define LSTRB 48                 // bytes per LDS row: 32 + 16 pad
#define KITER (D_DIM / BK)       // 32

__global__ __launch_bounds__(256) void gemm_fp8_kernel(
    const unsigned char* __restrict__ A,
    const unsigned char* __restrict__ Bm,
    __hip_bfloat16* __restrict__ Cm) {
  __shared__ alignas(16) unsigned char lA[2][TMM * LSTRB];  // 2 x 6 KB
  __shared__ alignas(16) unsigned char lB[2][TNN * LSTRB];  // 2 x 3 KB
  const int t = threadIdx.x;
  const int bn = blockIdx.x;                 // 48 N-blocks
  const int bm = blockIdx.y;                 // 32 M-blocks
  const unsigned char* Ag = A + (size_t)bm * TMM * D_DIM;
  const unsigned char* Bg = Bm + (size_t)bn * TNN * D_DIM;

  const int lane = t & 63, wv = t >> 6;
  const int wm = (wv >> 1) * 64, wn = (wv & 1) * 32;
  const int quad = lane >> 4, l16 = lane & 15;

  // staging: A = 256 16B chunks (1/thread); B = 128 chunks (threads 0..127).
  const int srow = t >> 1, shalf = (t & 1) * 16;
  const unsigned char* ap = Ag + (size_t)srow * D_DIM + shalf;
  const int wroffA = srow * LSTRB + shalf;
  const bool doB = (t < 128);                 // wave-uniform (waves 0,1)
  const int srowB = (t & 127) >> 1;
  const unsigned char* bp = Bg + (size_t)srowB * D_DIM + shalf;
  const int wroffB = srowB * LSTRB + shalf;

  floatx4 acc[4][2] = {};

  // prologue: tile 0 -> buf0; issue tile 1 loads; barrier (no vmcnt drain)
  float4 a0 = *(const float4*)(ap);
  float4 b0;
  if (doB) b0 = *(const float4*)(bp);
  *(float4*)(lA[0] + wroffA) = a0;
  if (doB) *(float4*)(lB[0] + wroffB) = b0;
  a0 = *(const float4*)(ap + BK);
  if (doB) b0 = *(const float4*)(bp + BK);
  LDS_BARRIER();

#pragma unroll 2
  for (int i = 0; i < KITER; ++i) {
    const int p = i & 1;
    if (i < KITER - 1) {
      *(float4*)(lA[1 - p] + wroffA) = a0;    // tile i+1 -> buf[1-p]
      if (doB) *(float4*)(lB[1 - p] + wroffB) = b0;
      const int nk = (i + 2 < KITER ? i + 2 : KITER - 1) * BK;
      a0 = *(const float4*)(ap + nk);         // issue tile i+2 loads
      if (doB) b0 = *(const float4*)(bp + nk);
    }
    long long af[4], bfr[2];
#pragma unroll
    for (int x = 0; x < 4; ++x)
      af[x] = *(const long long*)(lA[p] + (wm + x * 16 + l16) * LSTRB + quad * 8);
#pragma unroll
    for (int y = 0; y < 2; ++y)
      bfr[y] = *(const long long*)(lB[p] + (wn + y * 16 + l16) * LSTRB + quad * 8);
#pragma unroll
    for (int x = 0; x < 4; ++x)
#pragma unroll
      for (int y = 0; y < 2; ++y)
        acc[x][y] = __builtin_amdgcn_mfma_f32_16x16x32_fp8_fp8(af[x], bfr[y], acc[x][y], 0, 0, 0);
    LDS_BARRIER();
  }

  unsigned short* Cu = (unsigned short*)Cm;
#pragma unroll
  for (int x = 0; x < 4; ++x)
#pragma unroll
    for (int y = 0; y < 2; ++y)
#pragma unroll
      for (int r = 0; r < 4; ++r) {
        const int row = bm * TMM + wm + x * 16 + quad * 4 + r;
        const int col = bn * TNN + wn + y * 16 + l16;
        __hip_bfloat16 h = __float2bfloat16(acc[x][y][r]);
        Cu[(size_t)row * N_TOT + col] = *(unsigned short*)&h;
      }
}

// ---------------------------------------------------------------------------
// One WAVE per row, single-pass reductions (unchanged from R10/R12).
// ---------------------------------------------------------------------------
__global__ __launch_bounds__(256) void row_reduce_kernel(
    const __hip_bfloat16* __restrict__ sims, const int* __restrict__ labels,
    const int* __restrict__ ppl,
    float* __restrict__ pos_o, float* __restrict__ inf_o, float* __restrict__ crs_o) {
  const int wv = threadIdx.x >> 6, lane = threadIdx.x & 63;
  const int b = blockIdx.x * 4 + wv;
  const unsigned short* row = (const unsigned short*)sims + (size_t)b * N_TOT;
  const int lab = labels[b];

  // ---- intra: cols [0, 1000); [1000,1024) are exact zeros (pad), masked ----
  {
    const int i1 = 512 + lane * 8;
    float vi[16];
    bf16x8 u0 = *(const bf16x8*)(row + lane * 8);
    bf16x8 u1 = *(const bf16x8*)(row + i1);
#pragma unroll
    for (int j = 0; j < 8; ++j) { vi[j] = (float)u0[j]; vi[8 + j] = (float)u1[j]; }
    float sum = 0.f, sq = 0.f, mx = -1e30f;
#pragma unroll
    for (int j = 0; j < 8; ++j) {
      float v = vi[j];
      sum += v; sq += v * v; mx = fmaxf(mx, v);
    }
#pragma unroll
    for (int j = 0; j < 8; ++j) {
      if (i1 + j < C_CUR) { float v = vi[8 + j]; sum += v; sq += v * v; mx = fmaxf(mx, v); }
    }
    sum = wave_sum(sum); sq = wave_sum(sq); mx = wave_max(mx);
    const float var = (sq - sum * sum / (float)C_CUR) / (float)(C_CUR - 1);
    const float sd = sqrtf(fmaxf(var, 0.f));
    const float temp = fminf(fmaxf(0.07f * (1.f + sd), 0.01f), 0.5f);
    const float it = 1.f / temp;
    float se = 0.f;
#pragma unroll
    for (int j = 0; j < 8; ++j) se += __expf((vi[j] - mx) * it);
#pragma unroll
    for (int j = 0; j < 8; ++j)
      if (i1 + j < C_CUR) se += __expf((vi[8 + j] - mx) * it);
    se = wave_sum(se);
    if (lane == 0) {
      __hip_bfloat16 hs;
      *(unsigned short*)&hs = row[lab];
      const float slab = __bfloat162float(hs);
      pos_o[b] = 1.f - slab;
      inf_o[b] = mx * it + logf(se) - slab * it;
    }
  }

  // ---- cross: cols [1024, 3072), masked by ppl != lab ----
  {
    const unsigned short* crow = row + C_PAD;
    float vc[32];
    unsigned mask = 0;
    float sum = 0.f, sq = 0.f, mx = -1e30f;
    int cnt = 0;
#pragma unroll
    for (int k = 0; k < 4; ++k) {
      const int base = k * 512 + lane * 8;
      bf16x8 u = *(const bf16x8*)(crow + base);
#pragma unroll
      for (int j = 0; j < 8; ++j) vc[k * 8 + j] = (float)u[j];
      if (base < P_PREV) {
        int4 p0 = *(const int4*)(ppl + base);
        int4 p1 = *(const int4*)(ppl + base + 4);
        const int pl[8] = {p0.x, p0.y, p0.z, p0.w, p1.x, p1.y, p1.z, p1.w};
#pragma unroll
        for (int j = 0; j < 8; ++j) {
          if (pl[j] != lab) {
            mask |= 1u << (k * 8 + j);
            float v = vc[k * 8 + j];
            sum += v; sq += v * v; mx = fmaxf(mx, v); ++cnt;
          }
        }
      }
    }
    sum = wave_sum(sum); sq = wave_sum(sq); mx = wave_max(mx);
    const float n = wave_sum((float)cnt);
    const float var = (sq - sum * sum / n) / (n - 1.f);
    const float sd = sqrtf(fmaxf(var, 0.f));
    const float ct = 2.f * fminf(fmaxf(0.07f * (1.f + sd), 0.01f), 0.5f);
    const float it = 1.f / ct;
    float se = 0.f;
#pragma unroll
    for (int e = 0; e < 32; ++e)
      if ((mask >> e) & 1u) se += __expf((vc[e] - mx) * it);
    se = wave_sum(se);
    if (lane == 0) crs_o[b] = mx * it + logf(se);
  }
}

// ---------------------------------------------------------------------------
__global__ __launch_bounds__(1024) void final_reduce_kernel(
    const float* __restrict__ pos_o, const float* __restrict__ inf_o,
    const float* __restrict__ crs_o, float* __restrict__ out) {
  const int t = threadIdx.x;
  __shared__ float sA[1024], sB[1024], sC[1024];
  float a = 0.f, bb = 0.f, c = 0.f;
  for (int i = t; i < B_ROWS; i += 1024) {
    a += pos_o[i]; bb += inf_o[i]; c += crs_o[i];
  }
  sA[t] = a; sB[t] = bb; sC[t] = c;
  __syncthreads();
  for (int o = 512; o > 0; o >>= 1) {
    if (t < o) { sA[t] += sA[t + o]; sB[t] += sB[t + o]; sC[t] += sC[t + o]; }
    __syncthreads();
  }
  if (t == 0) {
    const float invB = 1.f / (float)B_ROWS;
    const float pos = sA[0] * invB;
    const float neg = sB[0] * invB + 0.3f * sC[0] * invB;
    const float curr_beta = 0.5f * (0.1f + 0.9f * (1.0f / 1000.0f));  // step=1/warmup=1000
    out[0] = pos + curr_beta * neg;                                   // ALPHA=1
  }
}

// ---------------------------------------------------------------------------
extern "C" void kernel_launch(void* const* d_in, const int* in_sizes, int n_in,
                              void* d_out, int out_size, void* d_ws, size_t ws_size,
                              hipStream_t stream) {
  const float* features   = (const float*)d_in[0];
  const float* cur_proto  = (const float*)d_in[1];
  const float* prev_proto = (const float*)d_in[2];
  const int*   labels     = (const int*)d_in[3];
  const int*   ppl        = (const int*)d_in[4];

  char* w = (char*)d_ws;
  unsigned char* fn    = (unsigned char*)w;                                 // 4 MB
  unsigned char* proto = (unsigned char*)(w + (size_t)4 * 1024 * 1024);     // 3 MB
  __hip_bfloat16* sims = (__hip_bfloat16*)(w + (size_t)8 * 1024 * 1024);    // 24 MB
  char* tail = w + (size_t)8 * 1024 * 1024 + (size_t)B_ROWS * N_TOT * 2;
  float* pos_o = (float*)tail;
  float* inf_o = pos_o + B_ROWS;
  float* crs_o = inf_o + B_ROWS;

  norm_all_kernel<<<(B_ROWS + C_PAD + P_PAD) / 4, 256, 0, stream>>>(
      features, cur_proto, prev_proto, fn, proto);

  dim3 grid(N_TOT / TNN, B_ROWS / TMM);  // 48 x 32 = 1536 blocks
  gemm_fp8_kernel<<<grid, 256, 0, stream>>>(fn, proto, sims);

  row_reduce_kernel<<<B_ROWS / 4, 256, 0, stream>>>(sims, labels, ppl, pos_o, inf_o, crs_o);
  final_reduce_kernel<<<1, 1024, 0, stream>>>(pos_o, inf_o, crs_o, (float*)d_out);
}

// Round 15
// 121.922 us; speedup vs baseline: 1.0972x; 1.0972x over previous
//
#include <hip/hip_runtime.h>
#include <hip/hip_bf16.h>
#include <math.h>

typedef __attribute__((ext_vector_type(4))) float floatx4;
typedef __attribute__((ext_vector_type(8))) __bf16 bf16x8;

#define B_ROWS 4096
#define D_DIM  1024
#define C_CUR  1000
#define P_PREV 2000
#define C_PAD  1024
#define P_PAD  2048
#define N_TOT  (C_PAD + P_PAD)   // 3072

// NOTE: __builtin_amdgcn_global_load_lds is BANNED this session: 4/4 container
// deaths (R4-R6, R8) vs clean runs without.
// Barrier without vmcnt drain (prefetch loads stay in flight).
#define LDS_BARRIER() asm volatile("s_waitcnt lgkmcnt(0)\n\ts_barrier" ::: "memory")

__device__ __forceinline__ float wave_sum(float v) {
#pragma unroll
  for (int o = 32; o > 0; o >>= 1) v += __shfl_xor(v, o, 64);
  return v;
}
__device__ __forceinline__ float wave_max(float v) {
#pragma unroll
  for (int o = 32; o > 0; o >>= 1) v = fmaxf(v, __shfl_xor(v, o, 64));
  return v;
}

// float -> OCP e4m3fn, RNE, manual (values here are |x| <= 1, no NaN/inf).
__device__ __forceinline__ unsigned char f32_to_e4m3(float x) {
  unsigned u = __float_as_uint(x);
  unsigned s = (u >> 24) & 0x80u;
  float a = fabsf(x);
  if (a < 0.015625f) {                    // subnormal: step 2^-9
    int q = (int)rintf(a * 512.0f);       // 0..8; 8 rolls into exp=1,m=0 (2^-6)
    return (unsigned char)(s | (unsigned)q);
  }
  unsigned au = u & 0x7fffffffu;
  unsigned r = au + 0x0007ffffu + ((au >> 20) & 1u);  // RNE at bit 20
  int e = (int)(r >> 23) - 127;
  unsigned m = (r >> 20) & 7u;
  return (unsigned char)(s | ((unsigned)(e + 7) << 3) | m);
}

// ---------------------------------------------------------------------------
// Fused L2-normalize -> fp8 e4m3. One WAVE per row; lane owns 16 contiguous
// elements. Pad rows zero-filled.
// ---------------------------------------------------------------------------
__global__ __launch_bounds__(256) void norm_all_kernel(
    const float* __restrict__ features, const float* __restrict__ cur_proto,
    const float* __restrict__ prev_proto, unsigned char* __restrict__ fn,
    unsigned char* __restrict__ proto) {
  const int wv = threadIdx.x >> 6, lane = threadIdx.x & 63;
  const int r = blockIdx.x * 4 + wv;
  const float* src;
  unsigned char* dst;
  bool valid;
  if (r < B_ROWS) {
    src = features + (size_t)r * D_DIM;
    dst = fn + (size_t)r * D_DIM;
    valid = true;
  } else if (r < B_ROWS + C_PAD) {
    const int rr = r - B_ROWS;
    src = cur_proto + (size_t)rr * D_DIM;
    dst = proto + (size_t)rr * D_DIM;
    valid = rr < C_CUR;
  } else {
    const int rr = r - B_ROWS - C_PAD;
    src = prev_proto + (size_t)rr * D_DIM;
    dst = proto + (size_t)(C_PAD + rr) * D_DIM;
    valid = rr < P_PREV;
  }
  if (!valid) {
    uint4 z = {0, 0, 0, 0};
    *(uint4*)(dst + lane * 16) = z;
    return;
  }
  float4 v[4];
  float ss = 0.f;
#pragma unroll
  for (int k = 0; k < 4; ++k) {
    v[k] = *(const float4*)(src + lane * 16 + k * 4);
    ss += v[k].x * v[k].x + v[k].y * v[k].y + v[k].z * v[k].z + v[k].w * v[k].w;
  }
  ss = wave_sum(ss);
  const float inv = 1.0f / fmaxf(sqrtf(ss), 1e-12f);
  union { unsigned char b[16]; uint4 q; } o;
#pragma unroll
  for (int k = 0; k < 4; ++k) {
    o.b[k * 4 + 0] = f32_to_e4m3(v[k].x * inv);
    o.b[k * 4 + 1] = f32_to_e4m3(v[k].y * inv);
    o.b[k * 4 + 2] = f32_to_e4m3(v[k].z * inv);
    o.b[k * 4 + 3] = f32_to_e4m3(v[k].w * inv);
  }
  *(uint4*)(dst + lane * 16) = o.q;
}

// ---------------------------------------------------------------------------
// GEMM fp8 (R12, best measured): C = A*B^T, fp8 e4m3 in, bf16 out, fp32
// accum. 128x128 tile, BK=32B. LDS stride 48B. Double-buffered LDS +
// 1-deep register prefetch + lgkm-only s_barrier.
// C/D map (m89/m91): row=(lane>>4)*4+reg, col=lane&15.
// Session ledger: 128x64 tile (R14) -10us regression (doubled A-staging,
// conflicts); 2-deep prefetch + XCD swizzle (R13) neutral; bf16 variants
// all >= +1.6us. This configuration is the measured local optimum under
// the global_load_lds environment ban.
// ---------------------------------------------------------------------------
#define TM    128
#define BK    32
#define LSTRB 48                 // bytes per LDS row: 32 + 16 pad
#define KITER (D_DIM / BK)       // 32

__global__ __launch_bounds__(256) void gemm_fp8_kernel(
    const unsigned char* __restrict__ A,
    const unsigned char* __restrict__ Bm,
    __hip_bfloat16* __restrict__ Cm) {
  __shared__ alignas(16) unsigned char lA[2][TM * LSTRB];  // 2 x 6 KB
  __shared__ alignas(16) unsigned char lB[2][TM * LSTRB];  // 2 x 6 KB
  const int t = threadIdx.x;
  const int bm = blockIdx.y, bn = blockIdx.x;
  const unsigned char* Ag = A + (size_t)bm * TM * D_DIM;
  const unsigned char* Bg = Bm + (size_t)bn * TM * D_DIM;

  const int lane = t & 63, wv = t >> 6;
  const int wm = (wv >> 1) * 64, wn = (wv & 1) * 64;
  const int quad = lane >> 4, l16 = lane & 15;

  // staging: 256 16B chunks per matrix per tile = 1 per thread.
  const int srow = t >> 1, shalf = (t & 1) * 16;
  const unsigned char* ap = Ag + (size_t)srow * D_DIM + shalf;
  const unsigned char* bp = Bg + (size_t)srow * D_DIM + shalf;
  const int wroff = srow * LSTRB + shalf;

  floatx4 acc[4][4] = {};

  // prologue: tile 0 -> buf0; issue tile 1 loads; barrier (no vmcnt drain)
  float4 a0 = *(const float4*)(ap);
  float4 b0 = *(const float4*)(bp);
  *(float4*)(lA[0] + wroff) = a0;
  *(float4*)(lB[0] + wroff) = b0;
  a0 = *(const float4*)(ap + BK);
  b0 = *(const float4*)(bp + BK);
  LDS_BARRIER();

#pragma unroll 2
  for (int i = 0; i < KITER; ++i) {
    const int p = i & 1;
    if (i < KITER - 1) {
      *(float4*)(lA[1 - p] + wroff) = a0;   // tile i+1 -> buf[1-p]
      *(float4*)(lB[1 - p] + wroff) = b0;
      const int nk = (i + 2 < KITER) ? (i + 2) * BK : (KITER - 1) * BK;
      a0 = *(const float4*)(ap + nk);       // issue tile i+2 loads
      b0 = *(const float4*)(bp + nk);
    }
    long long af[4], bfr[4];
#pragma unroll
    for (int x = 0; x < 4; ++x)
      af[x] = *(const long long*)(lA[p] + (wm + x * 16 + l16) * LSTRB + quad * 8);
#pragma unroll
    for (int y = 0; y < 4; ++y)
      bfr[y] = *(const long long*)(lB[p] + (wn + y * 16 + l16) * LSTRB + quad * 8);
#pragma unroll
    for (int x = 0; x < 4; ++x)
#pragma unroll
      for (int y = 0; y < 4; ++y)
        acc[x][y] = __builtin_amdgcn_mfma_f32_16x16x32_fp8_fp8(af[x], bfr[y], acc[x][y], 0, 0, 0);
    LDS_BARRIER();
  }

  unsigned short* Cu = (unsigned short*)Cm;
#pragma unroll
  for (int x = 0; x < 4; ++x)
#pragma unroll
    for (int y = 0; y < 4; ++y)
#pragma unroll
      for (int r = 0; r < 4; ++r) {
        const int row = bm * TM + wm + x * 16 + quad * 4 + r;
        const int col = bn * TM + wn + y * 16 + l16;
        __hip_bfloat16 h = __float2bfloat16(acc[x][y][r]);
        Cu[(size_t)row * N_TOT + col] = *(unsigned short*)&h;
      }
}

// ---------------------------------------------------------------------------
// One WAVE per row, single-pass reductions (R10/R12).
// ---------------------------------------------------------------------------
__global__ __launch_bounds__(256) void row_reduce_kernel(
    const __hip_bfloat16* __restrict__ sims, const int* __restrict__ labels,
    const int* __restrict__ ppl,
    float* __restrict__ pos_o, float* __restrict__ inf_o, float* __restrict__ crs_o) {
  const int wv = threadIdx.x >> 6, lane = threadIdx.x & 63;
  const int b = blockIdx.x * 4 + wv;
  const unsigned short* row = (const unsigned short*)sims + (size_t)b * N_TOT;
  const int lab = labels[b];

  // ---- intra: cols [0, 1000); [1000,1024) are exact zeros (pad), masked ----
  {
    const int i1 = 512 + lane * 8;
    float vi[16];
    bf16x8 u0 = *(const bf16x8*)(row + lane * 8);
    bf16x8 u1 = *(const bf16x8*)(row + i1);
#pragma unroll
    for (int j = 0; j < 8; ++j) { vi[j] = (float)u0[j]; vi[8 + j] = (float)u1[j]; }
    float sum = 0.f, sq = 0.f, mx = -1e30f;
#pragma unroll
    for (int j = 0; j < 8; ++j) {
      float v = vi[j];
      sum += v; sq += v * v; mx = fmaxf(mx, v);
    }
#pragma unroll
    for (int j = 0; j < 8; ++j) {
      if (i1 + j < C_CUR) { float v = vi[8 + j]; sum += v; sq += v * v; mx = fmaxf(mx, v); }
    }
    sum = wave_sum(sum); sq = wave_sum(sq); mx = wave_max(mx);
    const float var = (sq - sum * sum / (float)C_CUR) / (float)(C_CUR - 1);
    const float sd = sqrtf(fmaxf(var, 0.f));
    const float temp = fminf(fmaxf(0.07f * (1.f + sd), 0.01f), 0.5f);
    const float it = 1.f / temp;
    float se = 0.f;
#pragma unroll
    for (int j = 0; j < 8; ++j) se += __expf((vi[j] - mx) * it);
#pragma unroll
    for (int j = 0; j < 8; ++j)
      if (i1 + j < C_CUR) se += __expf((vi[8 + j] - mx) * it);
    se = wave_sum(se);
    if (lane == 0) {
      __hip_bfloat16 hs;
      *(unsigned short*)&hs = row[lab];
      const float slab = __bfloat162float(hs);
      pos_o[b] = 1.f - slab;
      inf_o[b] = mx * it + logf(se) - slab * it;
    }
  }

  // ---- cross: cols [1024, 3072), masked by ppl != lab ----
  {
    const unsigned short* crow = row + C_PAD;
    float vc[32];
    unsigned mask = 0;
    float sum = 0.f, sq = 0.f, mx = -1e30f;
    int cnt = 0;
#pragma unroll
    for (int k = 0; k < 4; ++k) {
      const int base = k * 512 + lane * 8;
      bf16x8 u = *(const bf16x8*)(crow + base);
#pragma unroll
      for (int j = 0; j < 8; ++j) vc[k * 8 + j] = (float)u[j];
      if (base < P_PREV) {
        int4 p0 = *(const int4*)(ppl + base);
        int4 p1 = *(const int4*)(ppl + base + 4);
        const int pl[8] = {p0.x, p0.y, p0.z, p0.w, p1.x, p1.y, p1.z, p1.w};
#pragma unroll
        for (int j = 0; j < 8; ++j) {
          if (pl[j] != lab) {
            mask |= 1u << (k * 8 + j);
            float v = vc[k * 8 + j];
            sum += v; sq += v * v; mx = fmaxf(mx, v); ++cnt;
          }
        }
      }
    }
    sum = wave_sum(sum); sq = wave_sum(sq); mx = wave_max(mx);
    const float n = wave_sum((float)cnt);
    const float var = (sq - sum * sum / n) / (n - 1.f);
    const float sd = sqrtf(fmaxf(var, 0.f));
    const float ct = 2.f * fminf(fmaxf(0.07f * (1.f + sd), 0.01f), 0.5f);
    const float it = 1.f / ct;
    float se = 0.f;
#pragma unroll
    for (int e = 0; e < 32; ++e)
      if ((mask >> e) & 1u) se += __expf((vc[e] - mx) * it);
    se = wave_sum(se);
    if (lane == 0) crs_o[b] = mx * it + logf(se);
  }
}

// ---------------------------------------------------------------------------
__global__ __launch_bounds__(1024) void final_reduce_kernel(
    const float* __restrict__ pos_o, const float* __restrict__ inf_o,
    const float* __restrict__ crs_o, float* __restrict__ out) {
  const int t = threadIdx.x;
  __shared__ float sA[1024], sB[1024], sC[1024];
  float a = 0.f, bb = 0.f, c = 0.f;
  for (int i = t; i < B_ROWS; i += 1024) {
    a += pos_o[i]; bb += inf_o[i]; c += crs_o[i];
  }
  sA[t] = a; sB[t] = bb; sC[t] = c;
  __syncthreads();
  for (int o = 512; o > 0; o >>= 1) {
    if (t < o) { sA[t] += sA[t + o]; sB[t] += sB[t + o]; sC[t] += sC[t + o]; }
    __syncthreads();
  }
  if (t == 0) {
    const float invB = 1.f / (float)B_ROWS;
    const float pos = sA[0] * invB;
    const float neg = sB[0] * invB + 0.3f * sC[0] * invB;
    const float curr_beta = 0.5f * (0.1f + 0.9f * (1.0f / 1000.0f));  // step=1/warmup=1000
    out[0] = pos + curr_beta * neg;                                   // ALPHA=1
  }
}

// ---------------------------------------------------------------------------
extern "C" void kernel_launch(void* const* d_in, const int* in_sizes, int n_in,
                              void* d_out, int out_size, void* d_ws, size_t ws_size,
                              hipStream_t stream) {
  const float* features   = (const float*)d_in[0];
  const float* cur_proto  = (const float*)d_in[1];
  const float* prev_proto = (const float*)d_in[2];
  const int*   labels     = (const int*)d_in[3];
  const int*   ppl        = (const int*)d_in[4];

  char* w = (char*)d_ws;
  unsigned char* fn    = (unsigned char*)w;                                 // 4 MB
  unsigned char* proto = (unsigned char*)(w + (size_t)4 * 1024 * 1024);     // 3 MB
  __hip_bfloat16* sims = (__hip_bfloat16*)(w + (size_t)8 * 1024 * 1024);    // 24 MB
  char* tail = w + (size_t)8 * 1024 * 1024 + (size_t)B_ROWS * N_TOT * 2;
  float* pos_o = (float*)tail;
  float* inf_o = pos_o + B_ROWS;
  float* crs_o = inf_o + B_ROWS;

  norm_all_kernel<<<(B_ROWS + C_PAD + P_PAD) / 4, 256, 0, stream>>>(
      features, cur_proto, prev_proto, fn, proto);

  gemm_fp8_kernel<<<dim3(N_TOT / TM, B_ROWS / TM), 256, 0, stream>>>(fn, proto, sims);

  row_reduce_kernel<<<B_ROWS / 4, 256, 0, stream>>>(sims, labels, ppl, pos_o, inf_o, crs_o);
  final_reduce_kernel<<<1, 1024, 0, stream>>>(pos_o, inf_o, crs_o, (float*)d_out);
}